// Round 1
// baseline (81.536 us; speedup 1.0000x reference)
//
#include <hip/hip_runtime.h>
#include <math.h>

// PCEN: x [16,1,128,2048] f32, params alpha/delta/r [128] (log-space).
// smoother m[t] = (1-s) m[t-1] + s x[t], m[-1] = x[0]  (== reference's dense
// triangular matmul, verified algebraically).
// out[b, t, band] = (x*smooth + d)^rr - d^rr, smooth = exp(-a*(log(eps)+log1p(m/eps)))
//
// Layout: 1 block = (batch b, group of 8 bands), 8 waves, wave w owns band bg*8+w.
// Lane l owns t = 32l .. 32l+31 (contiguous): local serial scan + decayed
// Kogge-Stone shuffle scan over lane carries + fixup. pcen staged through
// padded LDS tile ([band][lane*33+k] + plane pad 8 -> bank-conflict free),
// then written t-major: each wave store = 8 t x 8 bands = 32B-aligned segments.

#define T_LEN   2048
#define NBANDS  128
#define PLANE   2120   // 64*33 + 8 pad

__global__ __launch_bounds__(512) void pcen_kernel(
    const float* __restrict__ x,
    const float* __restrict__ alpha,
    const float* __restrict__ delta,
    const float* __restrict__ r,
    float* __restrict__ out)
{
    __shared__ float tile[8 * PLANE];

    const int tid  = threadIdx.x;
    const int w    = tid >> 6;    // wave id = band index within group
    const int lane = tid & 63;
    const int bid  = blockIdx.x;
    const int b    = bid >> 4;    // 16 band-groups per batch
    const int bg   = bid & 15;
    const int band = bg * 8 + w;

    // s = (sqrt(1+4*T_VAL^2)-1) / (2*T_VAL^2), fp32 like the reference
    const float s = (sqrtf(262145.0f) - 1.0f) / 131072.0f;
    const float g = 1.0f - s;
    // g32 = g^32 via iterated squaring
    float g32 = g * g;            // ^2
    g32 *= g32;                   // ^4
    g32 *= g32;                   // ^8
    g32 *= g32;                   // ^16
    g32 *= g32;                   // ^32

    const float a    = __expf(alpha[band]);
    const float dd   = __expf(delta[band]);
    const float rr   = __expf(r[band]);
    const float dpow = __expf(rr * delta[band]);   // d^rr = exp(rr * log d)
    const float LOG_EPS = -11.512925465f;          // log(1e-5), fp32
    const float INV_EPS = 1.0e5f;

    const size_t row = ((size_t)b * NBANDS + band) * T_LEN;
    const float* xp  = x + row + (size_t)lane * 32;

    // ---- load 32 contiguous x into registers (8x float4) ----
    float xs[32];
    #pragma unroll
    for (int j = 0; j < 8; ++j) {
        const float4 v4 = *reinterpret_cast<const float4*>(xp + j * 4);
        xs[j*4+0] = v4.x; xs[j*4+1] = v4.y; xs[j*4+2] = v4.z; xs[j*4+3] = v4.w;
    }

    // ---- local scan for lane carry (lane 0 seeds virtual m[-1] = x[0]) ----
    float m = (lane == 0) ? xs[0] : 0.0f;
    #pragma unroll
    for (int k = 0; k < 32; ++k) m = fmaf(g, m, s * xs[k]);

    // ---- decayed Kogge-Stone inclusive scan of lane carries ----
    float v = m;
    float f = g32;
    #pragma unroll
    for (int off = 1; off < 64; off <<= 1) {
        float u = __shfl_up(v, off, 64);
        if (lane >= off) v = fmaf(f, u, v);
        f = f * f;
    }
    // exclusive: carry into this lane's chunk = m at t = 32*lane - 1
    float carry = __shfl_up(v, 1, 64);
    if (lane == 0) carry = xs[0];

    // ---- fixup + pcen + LDS stage ----
    float* tw = tile + w * PLANE + lane * 33;
    m = carry;
    #pragma unroll
    for (int k = 0; k < 32; ++k) {
        m = fmaf(g, m, s * xs[k]);                         // smoother[t]
        float lg     = LOG_EPS + __logf(fmaf(m, INV_EPS, 1.0f));
        float smooth = __expf(-a * lg);
        float base   = fmaf(xs[k], smooth, dd);
        float o      = __expf(rr * __logf(base)) - dpow;
        tw[k] = o;
    }
    __syncthreads();

    // ---- t-major coalesced write: out[b][t][band] ----
    // thread i: band-within-group wp = i&7, t offset tof = i>>3 (0..63)
    const int wp  = tid & 7;
    const int tof = tid >> 3;
    float* op = out + (size_t)b * T_LEN * NBANDS + bg * 8;
    #pragma unroll 4
    for (int c = 0; c < 32; ++c) {
        int t = c * 64 + tof;
        int l = t >> 5;
        int k = t & 31;
        op[(size_t)t * NBANDS + wp] = tile[wp * PLANE + l * 33 + k];
    }
}

extern "C" void kernel_launch(void* const* d_in, const int* in_sizes, int n_in,
                              void* d_out, int out_size, void* d_ws, size_t ws_size,
                              hipStream_t stream) {
    const float* x     = (const float*)d_in[0];
    const float* alpha = (const float*)d_in[1];
    const float* delta = (const float*)d_in[2];
    const float* r     = (const float*)d_in[3];
    float* out = (float*)d_out;

    // 16 batches x 16 band-groups(8 bands) = 256 blocks, 512 threads (8 waves)
    hipLaunchKernelGGL(pcen_kernel, dim3(16 * 16), dim3(512), 0, stream,
                       x, alpha, delta, r, out);
}